// Round 5
// baseline (434.701 us; speedup 1.0000x reference)
//
#include <hip/hip_runtime.h>
#include <hip/hip_fp16.h>

#define CHUNK 1024
#define NBKT 8     // per-node atomic-counter buckets

typedef _Float16 half8 __attribute__((ext_vector_type(8)));
typedef float floatx4 __attribute__((ext_vector_type(4)));

__device__ __forceinline__ unsigned int pack2(float a, float b) {
    __half2 h = __floats2half2_rn(a, b);
    return *(unsigned int*)&h;
}
__device__ __forceinline__ float2 unpack2(unsigned int u) {
    __half2 h = *(__half2*)&u;
    return __half22float2(h);
}

// ===========================================================================
// degree count (src-only read).  bucket = (e>>8)&7 matches edge_mlp1's.
// ===========================================================================
__global__ __launch_bounds__(256) void count_deg(
    const int* __restrict__ ei, int* __restrict__ deg, int E)
{
    int e = blockIdx.x * 256 + threadIdx.x;
    if (e >= E) return;
    atomicAdd(&deg[(size_t)ei[e] * NBKT + ((e >> 8) & (NBKT - 1))], 1);
}

__global__ __launch_bounds__(256) void scan_chunk_sums(
    const int* __restrict__ v, int* __restrict__ csum, int N)
{
    __shared__ int s[256];
    int base = blockIdx.x * CHUNK;
    int t = threadIdx.x;
    int acc = 0;
    #pragma unroll
    for (int i = 0; i < CHUNK / 256; ++i) {
        int idx = base + t + i * 256;
        if (idx < N) acc += v[idx];
    }
    s[t] = acc; __syncthreads();
    for (int o = 128; o > 0; o >>= 1) {
        if (t < o) s[t] += s[t + o];
        __syncthreads();
    }
    if (t == 0) csum[blockIdx.x] = s[0];
}

__global__ __launch_bounds__(256) void scan_chunk_off(
    const int* __restrict__ csum, int* __restrict__ coff, int nch)
{
    __shared__ int s[256];
    __shared__ int carry;
    int t = threadIdx.x;
    if (t == 0) carry = 0;
    __syncthreads();
    for (int base = 0; base < nch; base += 256) {
        int v = (base + t < nch) ? csum[base + t] : 0;
        s[t] = v; __syncthreads();
        for (int o = 1; o < 256; o <<= 1) {
            int add = (t >= o) ? s[t - o] : 0;
            __syncthreads();
            s[t] += add;
            __syncthreads();
        }
        int excl = carry + (t > 0 ? s[t - 1] : 0);
        if (base + t < nch) coff[base + t] = excl;
        __syncthreads();
        if (t == 0) carry += s[255];
        __syncthreads();
    }
}

// exclusive scan -> cursor (consumed destructively by edge_mlp1's atomicAdd;
// post-increment cursor[i] == start of sub-segment i+1, which is how the
// segmax kernels recover node boundaries)
__global__ __launch_bounds__(256) void scan_within_excl(
    const int* __restrict__ deg, int* __restrict__ pos,
    const int* __restrict__ coff, int N)
{
    __shared__ int s[256];
    int t = threadIdx.x;
    int base = blockIdx.x * CHUNK + t * 4;
    int v0 = 0, v1 = 0, v2 = 0, v3 = 0;
    if (base + 0 < N) v0 = deg[base + 0];
    if (base + 1 < N) v1 = deg[base + 1];
    if (base + 2 < N) v2 = deg[base + 2];
    if (base + 3 < N) v3 = deg[base + 3];
    s[t] = v0 + v1 + v2 + v3;
    __syncthreads();
    for (int o = 1; o < 256; o <<= 1) {
        int add = (t >= o) ? s[t - o] : 0;
        __syncthreads();
        s[t] += add;
        __syncthreads();
    }
    int run = coff[blockIdx.x] + (t > 0 ? s[t - 1] : 0);
    if (base + 0 < N) pos[base + 0] = run; run += v0;
    if (base + 1 < N) pos[base + 1] = run; run += v1;
    if (base + 2 < N) pos[base + 2] = run; run += v2;
    if (base + 3 < N) pos[base + 3] = run;
}

// ===========================================================================
// MFMA edge-MLP layer 1, ORIGINAL edge order (all streams coalesced).
// Side effects: cursor atomicAdd -> eid[p]=e (4 B permutation scatter, the
// ONLY scattered write in the pipeline); m2h[e] written coalesced.
//   16x16x32 layouts: A[m=lane&15][k=8q+j], B[k=8q+j][n=lane&15],
//   C/D: col=lane&15, row=4q+reg.
// ===========================================================================
__global__ __launch_bounds__(256) void edge_mlp1(
    const float* __restrict__ x,          // [N,4]
    const int*   __restrict__ ei,         // [2,E]
    const float* __restrict__ ea,         // [E,8] fp32 (converted inline)
    int*         __restrict__ cursor,     // [N*NBKT]
    int*         __restrict__ eid,        // [E] CSR permutation (out)
    const float* __restrict__ w1, const float* __restrict__ b1,  // 16x16
    const float* __restrict__ w2, const float* __restrict__ b2,  // 16x16
    _Float16* __restrict__ m2h,           // [E,16] original-order (out)
    int E)
{
    __shared__ _Float16 itm[4][4][16][24];   // [wave][tile][row][ch+pad]
    int tid = threadIdx.x;
    int w = tid >> 6, lane = tid & 63;
    int e16 = lane & 15, q = lane >> 4;
    int ebase = (blockIdx.x * 4 + w) << 6;
    int e = ebase + lane;

    // per-lane edge metadata + CSR slot (atomic issued early, used at end)
    int s_l = 0, d_l = 0, p_l = 0;
    if (e < E) {
        s_l = ei[e];
        d_l = ei[E + e];
        p_l = atomicAdd(&cursor[(size_t)s_l * NBKT + ((e >> 8) & (NBKT - 1))], 1);
    }

    half8 B1, B2;
    #pragma unroll
    for (int j = 0; j < 8; ++j) { B1[j] = (_Float16)0.f; B2[j] = (_Float16)0.f; }
    if (q < 2) {
        #pragma unroll
        for (int j = 0; j < 8; ++j) {
            B1[j] = (_Float16)w1[(8 * q + j) * 16 + e16];
            B2[j] = (_Float16)w2[(8 * q + j) * 16 + e16];
        }
    }
    float b1c = b1[e16], b2c = b2[e16];

    half8 A[4];
    #pragma unroll
    for (int t = 0; t < 4; ++t) {
        int st = __shfl(s_l, 16 * t + e16, 64);
        int dt = __shfl(d_l, 16 * t + e16, 64);
        half8 a;
        #pragma unroll
        for (int j = 0; j < 8; ++j) a[j] = (_Float16)0.f;
        int et = ebase + 16 * t + e16;
        if (q == 0 && et < E) {
            float4 xs = *(const float4*)(x + (size_t)st * 4);
            float4 xd = *(const float4*)(x + (size_t)dt * 4);
            a[0] = (_Float16)xs.x; a[1] = (_Float16)xs.y;
            a[2] = (_Float16)xs.z; a[3] = (_Float16)xs.w;
            a[4] = (_Float16)xd.x; a[5] = (_Float16)xd.y;
            a[6] = (_Float16)xd.z; a[7] = (_Float16)xd.w;
        } else if (q == 1 && et < E) {
            float4 a0 = *(const float4*)(ea + (size_t)et * 8);
            float4 a1 = *(const float4*)(ea + (size_t)et * 8 + 4);
            a[0] = (_Float16)a0.x; a[1] = (_Float16)a0.y;
            a[2] = (_Float16)a0.z; a[3] = (_Float16)a0.w;
            a[4] = (_Float16)a1.x; a[5] = (_Float16)a1.y;
            a[6] = (_Float16)a1.z; a[7] = (_Float16)a1.w;
        }
        A[t] = a;
    }

    floatx4 C[4];
    #pragma unroll
    for (int t = 0; t < 4; ++t) {
        floatx4 c = {b1c, b1c, b1c, b1c};
        C[t] = __builtin_amdgcn_mfma_f32_16x16x32_f16(A[t], B1, c, 0, 0, 0);
    }
    #pragma unroll
    for (int t = 0; t < 4; ++t)
        #pragma unroll
        for (int i = 0; i < 4; ++i)
            itm[w][t][4 * q + i][e16] = (_Float16)fmaxf(C[t][i], 0.0f);
    __builtin_amdgcn_wave_barrier();

    half8 A2[4];
    #pragma unroll
    for (int t = 0; t < 4; ++t) {
        half8 a;
        #pragma unroll
        for (int j = 0; j < 8; ++j) a[j] = (_Float16)0.f;
        if (q < 2) a = *(const half8*)&itm[w][t][e16][8 * q];
        A2[t] = a;
    }
    __builtin_amdgcn_wave_barrier();
    floatx4 C2[4];
    #pragma unroll
    for (int t = 0; t < 4; ++t) {
        floatx4 c = {b2c, b2c, b2c, b2c};
        C2[t] = __builtin_amdgcn_mfma_f32_16x16x32_f16(A2[t], B2, c, 0, 0, 0);
    }
    #pragma unroll
    for (int t = 0; t < 4; ++t)
        #pragma unroll
        for (int i = 0; i < 4; ++i)
            itm[w][t][4 * q + i][e16] = (_Float16)C2[t][i];
    __builtin_amdgcn_wave_barrier();

    if (e < E) {
        half8 lo = *(const half8*)&itm[w][q][e16][0];
        half8 hi = *(const half8*)&itm[w][q][e16][8];
        *(half8*)(m2h + (size_t)e * 16)     = lo;   // coalesced
        *(half8*)(m2h + (size_t)e * 16 + 8) = hi;
        eid[p_l] = e;                               // 4 B permutation scatter
    }
}

// ===========================================================================
// MFMA edge-MLP layer 2, ORIGINAL edge order; hw gathers for C-init;
// coalesced m2h[e] write.  No scatter at all.
// ===========================================================================
__global__ __launch_bounds__(256) void edge_mlp2(
    const float* __restrict__ hw_s,            // [N,16] fp32 (cb1 folded)
    const unsigned short* __restrict__ hw_dh,  // [N,16] fp16
    const int*   __restrict__ ei,
    const float* __restrict__ ea,
    const float* __restrict__ w1,              // [40,16] rows 32:40 used
    const float* __restrict__ w2, const float* __restrict__ b2,
    _Float16* __restrict__ m2h, int E)
{
    __shared__ _Float16 itm[4][4][16][24];
    int tid = threadIdx.x;
    int w = tid >> 6, lane = tid & 63;
    int e16 = lane & 15, q = lane >> 4;
    const __half* hwd = (const __half*)hw_dh;
    int ebase = (blockIdx.x * 4 + w) << 6;
    int e = ebase + lane;

    int s_l = 0, d_l = 0;
    if (e < E) {
        s_l = ei[e];
        d_l = ei[E + e];
    }

    half8 B1, B2;
    #pragma unroll
    for (int j = 0; j < 8; ++j) { B1[j] = (_Float16)0.f; B2[j] = (_Float16)0.f; }
    if (q == 0) {
        #pragma unroll
        for (int j = 0; j < 8; ++j)
            B1[j] = (_Float16)w1[(32 + j) * 16 + e16];
    }
    if (q < 2) {
        #pragma unroll
        for (int j = 0; j < 8; ++j)
            B2[j] = (_Float16)w2[(8 * q + j) * 16 + e16];
    }
    float b2c = b2[e16];

    half8 A[4];
    #pragma unroll
    for (int t = 0; t < 4; ++t) {
        half8 a;
        #pragma unroll
        for (int j = 0; j < 8; ++j) a[j] = (_Float16)0.f;
        int et = ebase + 16 * t + e16;
        if (q == 0 && et < E) {
            float4 a0 = *(const float4*)(ea + (size_t)et * 8);
            float4 a1 = *(const float4*)(ea + (size_t)et * 8 + 4);
            a[0] = (_Float16)a0.x; a[1] = (_Float16)a0.y;
            a[2] = (_Float16)a0.z; a[3] = (_Float16)a0.w;
            a[4] = (_Float16)a1.x; a[5] = (_Float16)a1.y;
            a[6] = (_Float16)a1.z; a[7] = (_Float16)a1.w;
        }
        A[t] = a;
    }

    floatx4 C[4];
    #pragma unroll
    for (int t = 0; t < 4; ++t) {
        floatx4 c;
        #pragma unroll
        for (int i = 0; i < 4; ++i) {
            int li = 16 * t + 4 * q + i;
            int s = __shfl(s_l, li, 64);
            int d = __shfl(d_l, li, 64);
            int rr = ebase + li;
            float v = 0.0f;
            if (rr < E) {
                v = hw_s[(size_t)s * 16 + e16]
                  + __half2float(hwd[(size_t)d * 16 + e16]);
            }
            c[i] = v;
        }
        C[t] = __builtin_amdgcn_mfma_f32_16x16x32_f16(A[t], B1, c, 0, 0, 0);
    }
    #pragma unroll
    for (int t = 0; t < 4; ++t)
        #pragma unroll
        for (int i = 0; i < 4; ++i)
            itm[w][t][4 * q + i][e16] = (_Float16)fmaxf(C[t][i], 0.0f);
    __builtin_amdgcn_wave_barrier();

    half8 A2[4];
    #pragma unroll
    for (int t = 0; t < 4; ++t) {
        half8 a;
        #pragma unroll
        for (int j = 0; j < 8; ++j) a[j] = (_Float16)0.f;
        if (q < 2) a = *(const half8*)&itm[w][t][e16][8 * q];
        A2[t] = a;
    }
    __builtin_amdgcn_wave_barrier();
    floatx4 C2[4];
    #pragma unroll
    for (int t = 0; t < 4; ++t) {
        floatx4 c = {b2c, b2c, b2c, b2c};
        C2[t] = __builtin_amdgcn_mfma_f32_16x16x32_f16(A2[t], B2, c, 0, 0, 0);
    }
    #pragma unroll
    for (int t = 0; t < 4; ++t)
        #pragma unroll
        for (int i = 0; i < 4; ++i)
            itm[w][t][4 * q + i][e16] = (_Float16)C2[t][i];
    __builtin_amdgcn_wave_barrier();

    if (e < E) {
        half8 lo = *(const half8*)&itm[w][q][e16][0];
        half8 hi = *(const half8*)&itm[w][q][e16][8];
        *(half8*)(m2h + (size_t)e * 16)     = lo;
        *(half8*)(m2h + (size_t)e * 16 + 8) = hi;
    }
}

// ===========================================================================
// Streaming segment-max (8 lanes/node) via eid indirection + fused epilogues.
// Boundaries from POST-INCREMENT cursor: start(n)=cur[n*NBKT-1],
// end(n)=cur[(n+1)*NBKT-1].
// ===========================================================================
__global__ __launch_bounds__(256) void segmax1_hw(
    const _Float16* __restrict__ m2h, const int* __restrict__ eid,
    const int* __restrict__ cur,
    const float* __restrict__ cw1, const float* __restrict__ cb1,
    float* __restrict__ hw_s, unsigned short* __restrict__ hw_dh,
    int N, int E)
{
    int tid = threadIdx.x;
    int n = blockIdx.x * 32 + (tid >> 3);
    if (n >= N) return;
    int g = tid & 7;
    int start = (n == 0) ? 0 : cur[(size_t)n * NBKT - 1];
    int end = cur[(size_t)(n + 1) * NBKT - 1];

    float acc[16];
    #pragma unroll
    for (int j = 0; j < 16; ++j) acc[j] = 0.0f;

    for (int k = start + g; k < end; k += 8) {
        int idx = eid[k];
        uint4 u0 = *(const uint4*)(m2h + (size_t)idx * 16);
        uint4 u1 = *(const uint4*)(m2h + (size_t)idx * 16 + 8);
        float2 f;
        f = unpack2(u0.x); acc[0]  = fmaxf(acc[0],  f.x); acc[1]  = fmaxf(acc[1],  f.y);
        f = unpack2(u0.y); acc[2]  = fmaxf(acc[2],  f.x); acc[3]  = fmaxf(acc[3],  f.y);
        f = unpack2(u0.z); acc[4]  = fmaxf(acc[4],  f.x); acc[5]  = fmaxf(acc[5],  f.y);
        f = unpack2(u0.w); acc[6]  = fmaxf(acc[6],  f.x); acc[7]  = fmaxf(acc[7],  f.y);
        f = unpack2(u1.x); acc[8]  = fmaxf(acc[8],  f.x); acc[9]  = fmaxf(acc[9],  f.y);
        f = unpack2(u1.y); acc[10] = fmaxf(acc[10], f.x); acc[11] = fmaxf(acc[11], f.y);
        f = unpack2(u1.z); acc[12] = fmaxf(acc[12], f.x); acc[13] = fmaxf(acc[13], f.y);
        f = unpack2(u1.w); acc[14] = fmaxf(acc[14], f.x); acc[15] = fmaxf(acc[15], f.y);
    }
    #pragma unroll
    for (int mask = 1; mask < 8; mask <<= 1) {
        #pragma unroll
        for (int j = 0; j < 16; ++j)
            acc[j] = fmaxf(acc[j], __shfl_xor(acc[j], mask, 64));
    }

    int j0 = 2 * g, j1 = 2 * g + 1;
    float hs0 = cb1[j0], hs1 = cb1[j1], hd0 = 0.0f, hd1 = 0.0f;
    #pragma unroll
    for (int k = 0; k < 16; ++k) {
        float ak = acc[k];
        hs0 = fmaf(ak, cw1[k * 16 + j0], hs0);
        hs1 = fmaf(ak, cw1[k * 16 + j1], hs1);
        hd0 = fmaf(ak, cw1[(16 + k) * 16 + j0], hd0);
        hd1 = fmaf(ak, cw1[(16 + k) * 16 + j1], hd1);
    }
    *(float2*)(hw_s + (size_t)n * 16 + j0) = make_float2(hs0, hs1);
    ((unsigned int*)hw_dh)[(size_t)n * 8 + g] = pack2(hd0, hd1);
}

__global__ __launch_bounds__(256) void segmax2_head(
    const _Float16* __restrict__ m2h, const int* __restrict__ eid,
    const int* __restrict__ cur,
    const float* __restrict__ l1w, const float* __restrict__ l1b,
    const float* __restrict__ l2w, const float* __restrict__ l2b,
    float* __restrict__ out, int N, int E)
{
    int tid = threadIdx.x;
    int n = blockIdx.x * 32 + (tid >> 3);
    if (n >= N) return;
    int g = tid & 7;
    int start = (n == 0) ? 0 : cur[(size_t)n * NBKT - 1];
    int end = cur[(size_t)(n + 1) * NBKT - 1];

    float acc[16];
    #pragma unroll
    for (int j = 0; j < 16; ++j) acc[j] = 0.0f;

    for (int k = start + g; k < end; k += 8) {
        int idx = eid[k];
        uint4 u0 = *(const uint4*)(m2h + (size_t)idx * 16);
        uint4 u1 = *(const uint4*)(m2h + (size_t)idx * 16 + 8);
        float2 f;
        f = unpack2(u0.x); acc[0]  = fmaxf(acc[0],  f.x); acc[1]  = fmaxf(acc[1],  f.y);
        f = unpack2(u0.y); acc[2]  = fmaxf(acc[2],  f.x); acc[3]  = fmaxf(acc[3],  f.y);
        f = unpack2(u0.z); acc[4]  = fmaxf(acc[4],  f.x); acc[5]  = fmaxf(acc[5],  f.y);
        f = unpack2(u0.w); acc[6]  = fmaxf(acc[6],  f.x); acc[7]  = fmaxf(acc[7],  f.y);
        f = unpack2(u1.x); acc[8]  = fmaxf(acc[8],  f.x); acc[9]  = fmaxf(acc[9],  f.y);
        f = unpack2(u1.y); acc[10] = fmaxf(acc[10], f.x); acc[11] = fmaxf(acc[11], f.y);
        f = unpack2(u1.z); acc[12] = fmaxf(acc[12], f.x); acc[13] = fmaxf(acc[13], f.y);
        f = unpack2(u1.w); acc[14] = fmaxf(acc[14], f.x); acc[15] = fmaxf(acc[15], f.y);
    }
    #pragma unroll
    for (int mask = 1; mask < 8; mask <<= 1) {
        #pragma unroll
        for (int j = 0; j < 16; ++j)
            acc[j] = fmaxf(acc[j], __shfl_xor(acc[j], mask, 64));
    }

    float t2[16];
    #pragma unroll
    for (int j = 0; j < 16; ++j) t2[j] = l1b[j];
    #pragma unroll
    for (int kk = 0; kk < 16; ++kk) {
        float ak = acc[kk];
        #pragma unroll
        for (int j = 0; j < 16; ++j) t2[j] = fmaf(ak, l1w[kk * 16 + j], t2[j]);
    }
    float r2 = l2b[0];
    #pragma unroll
    for (int j = 0; j < 16; ++j) r2 = fmaf(fmaxf(t2[j], 0.0f), l2w[j], r2);
    if (g == 0) out[n] = r2;
}

// ===========================================================================
extern "C" void kernel_launch(void* const* d_in, const int* in_sizes, int n_in,
                              void* d_out, int out_size, void* d_ws, size_t ws_size,
                              hipStream_t stream)
{
    const float* x     = (const float*)d_in[0];
    const int*   ei    = (const int*)  d_in[1];
    const float* ea    = (const float*)d_in[2];
    const float* c1_w1 = (const float*)d_in[3];
    const float* c1_b1 = (const float*)d_in[4];
    const float* c1_w2 = (const float*)d_in[5];
    const float* c1_b2 = (const float*)d_in[6];
    const float* c2_w1 = (const float*)d_in[7];
    const float* c2_b1 = (const float*)d_in[8];
    const float* c2_w2 = (const float*)d_in[9];
    const float* c2_b2 = (const float*)d_in[10];
    const float* l1_w  = (const float*)d_in[11];
    const float* l1_b  = (const float*)d_in[12];
    const float* l2_w  = (const float*)d_in[13];
    const float* l2_b  = (const float*)d_in[14];
    float* out = (float*)d_out;

    const int N = in_sizes[0] / 4;   // 100000
    const int E = in_sizes[2] / 8;   // 1600000
    const int M = N * NBKT;
    const int nch = (M + CHUNK - 1) / CHUNK;

    const int BLK = 256;
    const int egrid = (E + BLK - 1) / BLK;
    const int ggrid = (N + 31) / 32;
    const int ntiles64 = (E + 63) >> 6;
    const int mgrid = (ntiles64 + 3) / 4;

    size_t szEid = ((size_t)E * 4 + 15) & ~(size_t)15;    // 6.4 MB
    size_t szM2h = (size_t)E * 32;                        // 51.2 MB
    size_t szHws = (size_t)N * 16 * 4;                    // 6.4 MB
    size_t szHwd = (size_t)N * 16 * 2;                    // 3.2 MB
    size_t szCur = ((size_t)M * 4 + 15) & ~(size_t)15;    // 3.2 MB

    size_t eid_off  = 0;
    size_t m2h_off  = eid_off  + szEid;
    size_t hws_off  = m2h_off  + szM2h;
    size_t hwdh_off = hws_off  + szHws;
    size_t cur_off  = hwdh_off + szHwd;
    // overlays inside m2h (dead before edge_mlp1 writes it):
    size_t deg_off  = m2h_off;
    size_t cs_off   = deg_off + szCur;
    size_t cf_off   = cs_off + 16384;

    int*            eid  = (int*)  ((char*)d_ws + eid_off);
    _Float16*       m2h  = (_Float16*)((char*)d_ws + m2h_off);
    float*          hw_s = (float*)((char*)d_ws + hws_off);
    unsigned short* hwdh = (unsigned short*)((char*)d_ws + hwdh_off);
    int*            cur  = (int*)  ((char*)d_ws + cur_off);
    int*            deg  = (int*)  ((char*)d_ws + deg_off);
    int*            csum = (int*)  ((char*)d_ws + cs_off);
    int*            coff = (int*)  ((char*)d_ws + cf_off);

    hipMemsetAsync(deg, 0, (size_t)M * 4, stream);
    count_deg<<<egrid, BLK, 0, stream>>>(ei, deg, E);
    scan_chunk_sums<<<nch, BLK, 0, stream>>>(deg, csum, M);
    scan_chunk_off<<<1, 256, 0, stream>>>(csum, coff, nch);
    scan_within_excl<<<nch, BLK, 0, stream>>>(deg, cur, coff, M);
    edge_mlp1<<<mgrid, BLK, 0, stream>>>(x, ei, ea, cur, eid,
                                         c1_w1, c1_b1, c1_w2, c1_b2, m2h, E);
    segmax1_hw<<<ggrid, BLK, 0, stream>>>(m2h, eid, cur, c2_w1, c2_b1,
                                          hw_s, hwdh, N, E);
    edge_mlp2<<<mgrid, BLK, 0, stream>>>(hw_s, hwdh, ei, ea,
                                         c2_w1, c2_w2, c2_b2, m2h, E);
    segmax2_head<<<ggrid, BLK, 0, stream>>>(m2h, eid, cur, l1_w, l1_b,
                                            l2_w, l2_b, out, N, E);
}

// Round 6
// 352.997 us; speedup vs baseline: 1.2315x; 1.2315x over previous
//
#include <hip/hip_runtime.h>
#include <hip/hip_fp16.h>

#define CHUNK 1024
#define NBKT 8     // per-node atomic-counter buckets

typedef _Float16 half8 __attribute__((ext_vector_type(8)));
typedef _Float16 half4 __attribute__((ext_vector_type(4)));
typedef float floatx4 __attribute__((ext_vector_type(4)));

union H8 { half8 h; unsigned int u[4]; };

__device__ __forceinline__ half8 hmax8(half8 a, half8 b) {
#if __has_builtin(__builtin_elementwise_max)
    return __builtin_elementwise_max(a, b);
#else
    half8 r;
    #pragma unroll
    for (int j = 0; j < 8; ++j) r[j] = a[j] > b[j] ? a[j] : b[j];
    return r;
#endif
}

// ===========================================================================
// rank (atomicAdd over [N][NBKT] counters) + ea->fp16 + x->fp16, one pass.
// bucket = (e>>8)&7 so concurrent blocks hit different counters per node.
// ===========================================================================
__global__ __launch_bounds__(256) void rank_cvt(
    const int* __restrict__ ei, const float* __restrict__ ea,
    const float* __restrict__ x,
    int* __restrict__ deg, unsigned short* __restrict__ r,
    _Float16* __restrict__ eah, _Float16* __restrict__ xh,
    int E, int N)
{
    int e = blockIdx.x * 256 + threadIdx.x;
    if (e >= E) return;
    r[e] = (unsigned short)atomicAdd(&deg[(size_t)ei[e] * NBKT + ((e >> 8) & (NBKT - 1))], 1);
    float4 a0 = *(const float4*)(ea + (size_t)e * 8);
    float4 a1 = *(const float4*)(ea + (size_t)e * 8 + 4);
    half8 h;
    h[0] = (_Float16)a0.x; h[1] = (_Float16)a0.y;
    h[2] = (_Float16)a0.z; h[3] = (_Float16)a0.w;
    h[4] = (_Float16)a1.x; h[5] = (_Float16)a1.y;
    h[6] = (_Float16)a1.z; h[7] = (_Float16)a1.w;
    *(half8*)(eah + (size_t)e * 8) = h;
    if (e < N) {
        float4 xv = *(const float4*)(x + (size_t)e * 4);
        half4 hx;
        hx[0] = (_Float16)xv.x; hx[1] = (_Float16)xv.y;
        hx[2] = (_Float16)xv.z; hx[3] = (_Float16)xv.w;
        *(half4*)(xh + (size_t)e * 4) = hx;
    }
}

__global__ __launch_bounds__(256) void scan_chunk_sums(
    const int* __restrict__ v, int* __restrict__ csum, int N)
{
    __shared__ int s[256];
    int base = blockIdx.x * CHUNK;
    int t = threadIdx.x;
    int acc = 0;
    #pragma unroll
    for (int i = 0; i < CHUNK / 256; ++i) {
        int idx = base + t + i * 256;
        if (idx < N) acc += v[idx];
    }
    s[t] = acc; __syncthreads();
    for (int o = 128; o > 0; o >>= 1) {
        if (t < o) s[t] += s[t + o];
        __syncthreads();
    }
    if (t == 0) csum[blockIdx.x] = s[0];
}

__global__ __launch_bounds__(256) void scan_chunk_off(
    const int* __restrict__ csum, int* __restrict__ coff, int nch)
{
    __shared__ int s[256];
    __shared__ int carry;
    int t = threadIdx.x;
    if (t == 0) carry = 0;
    __syncthreads();
    for (int base = 0; base < nch; base += 256) {
        int v = (base + t < nch) ? csum[base + t] : 0;
        s[t] = v; __syncthreads();
        for (int o = 1; o < 256; o <<= 1) {
            int add = (t >= o) ? s[t - o] : 0;
            __syncthreads();
            s[t] += add;
            __syncthreads();
        }
        int excl = carry + (t > 0 ? s[t - 1] : 0);
        if (base + t < nch) coff[base + t] = excl;
        __syncthreads();
        if (t == 0) carry += s[255];
        __syncthreads();
    }
}

__global__ __launch_bounds__(256) void scan_within_excl(
    const int* __restrict__ deg, int* __restrict__ pos,
    const int* __restrict__ coff, int N)
{
    __shared__ int s[256];
    int t = threadIdx.x;
    int base = blockIdx.x * CHUNK + t * 4;
    int v0 = 0, v1 = 0, v2 = 0, v3 = 0;
    if (base + 0 < N) v0 = deg[base + 0];
    if (base + 1 < N) v1 = deg[base + 1];
    if (base + 2 < N) v2 = deg[base + 2];
    if (base + 3 < N) v3 = deg[base + 3];
    s[t] = v0 + v1 + v2 + v3;
    __syncthreads();
    for (int o = 1; o < 256; o <<= 1) {
        int add = (t >= o) ? s[t - o] : 0;
        __syncthreads();
        s[t] += add;
        __syncthreads();
    }
    int run = coff[blockIdx.x] + (t > 0 ? s[t - 1] : 0);
    if (base + 0 < N) pos[base + 0] = run; run += v0;
    if (base + 1 < N) pos[base + 1] = run; run += v1;
    if (base + 2 < N) pos[base + 2] = run; run += v2;
    if (base + 3 < N) pos[base + 3] = run;
}

// ===========================================================================
// conv1 edge-MLP: ONE 64-edge macro-tile per wave (4 x 16x16 MFMA tiles).
//   16x16x32 layouts: A[m=lane&15][k=8q+j], B[k=8q+j][n=lane&15],
//   C/D: col=lane&15, row=4q+reg.
// A k-map: q0 j0-3 = xh[src], j4-7 = xh[dst]; q1 j0-7 = eah.
// CSR slot: pos[src*NBKT+(e>>8)&7] + r[e]; 32 B scattered store (merges OK,
// measured round 2: WRITE ~= logical).
// ===========================================================================
__global__ __launch_bounds__(256) void edge_mlp1(
    const _Float16* __restrict__ xh,      // [N,4] fp16
    const int*   __restrict__ ei,         // [2,E]
    const _Float16* __restrict__ eah,     // [E,8] fp16
    const int*   __restrict__ pos,        // [N*NBKT] exclusive scan
    const unsigned short* __restrict__ r,
    const float* __restrict__ w1, const float* __restrict__ b1,  // 16x16
    const float* __restrict__ w2, const float* __restrict__ b2,  // 16x16
    _Float16* __restrict__ m2h,           // [E,16] CSR-ordered out
    int E)
{
    __shared__ _Float16 itm[4][4][16][24];
    int tid = threadIdx.x;
    int w = tid >> 6, lane = tid & 63;
    int e16 = lane & 15, q = lane >> 4;
    int ebase = (blockIdx.x * 4 + w) << 6;
    if (ebase >= E) return;
    int e = ebase + lane;

    int s_l = 0, d_l = 0, p_l = 0;
    if (e < E) {
        s_l = ei[e];
        d_l = ei[E + e];
        p_l = pos[(size_t)s_l * NBKT + ((e >> 8) & (NBKT - 1))] + (int)r[e];
    }

    half8 B1, B2;
    #pragma unroll
    for (int j = 0; j < 8; ++j) { B1[j] = (_Float16)0.f; B2[j] = (_Float16)0.f; }
    if (q < 2) {
        #pragma unroll
        for (int j = 0; j < 8; ++j) {
            B1[j] = (_Float16)w1[(8 * q + j) * 16 + e16];
            B2[j] = (_Float16)w2[(8 * q + j) * 16 + e16];
        }
    }
    float b1c = b1[e16], b2c = b2[e16];

    half8 A[4];
    #pragma unroll
    for (int t = 0; t < 4; ++t) {
        int st = __shfl(s_l, 16 * t + e16, 64);
        int dt = __shfl(d_l, 16 * t + e16, 64);
        half8 a;
        #pragma unroll
        for (int j = 0; j < 8; ++j) a[j] = (_Float16)0.f;
        int et = ebase + 16 * t + e16;
        if (q == 0 && et < E) {
            half4 hs = *(const half4*)(xh + (size_t)st * 4);   // 8 B gather
            half4 hd = *(const half4*)(xh + (size_t)dt * 4);
            a[0] = hs[0]; a[1] = hs[1]; a[2] = hs[2]; a[3] = hs[3];
            a[4] = hd[0]; a[5] = hd[1]; a[6] = hd[2]; a[7] = hd[3];
        } else if (q == 1 && et < E) {
            a = *(const half8*)(eah + (size_t)et * 8);
        }
        A[t] = a;
    }

    floatx4 C[4];
    #pragma unroll
    for (int t = 0; t < 4; ++t) {
        floatx4 c = {b1c, b1c, b1c, b1c};
        C[t] = __builtin_amdgcn_mfma_f32_16x16x32_f16(A[t], B1, c, 0, 0, 0);
    }
    #pragma unroll
    for (int t = 0; t < 4; ++t)
        #pragma unroll
        for (int i = 0; i < 4; ++i)
            itm[w][t][4 * q + i][e16] = (_Float16)fmaxf(C[t][i], 0.0f);
    __builtin_amdgcn_wave_barrier();

    half8 A2[4];
    #pragma unroll
    for (int t = 0; t < 4; ++t) {
        half8 a;
        #pragma unroll
        for (int j = 0; j < 8; ++j) a[j] = (_Float16)0.f;
        if (q < 2) a = *(const half8*)&itm[w][t][e16][8 * q];
        A2[t] = a;
    }
    __builtin_amdgcn_wave_barrier();
    floatx4 C2[4];
    #pragma unroll
    for (int t = 0; t < 4; ++t) {
        floatx4 c = {b2c, b2c, b2c, b2c};
        C2[t] = __builtin_amdgcn_mfma_f32_16x16x32_f16(A2[t], B2, c, 0, 0, 0);
    }
    #pragma unroll
    for (int t = 0; t < 4; ++t)
        #pragma unroll
        for (int i = 0; i < 4; ++i)
            itm[w][t][4 * q + i][e16] = (_Float16)C2[t][i];
    __builtin_amdgcn_wave_barrier();

    if (e < E) {
        half8 lo = *(const half8*)&itm[w][q][e16][0];
        half8 hi = *(const half8*)&itm[w][q][e16][8];
        *(half8*)(m2h + (size_t)p_l * 16)     = lo;
        *(half8*)(m2h + (size_t)p_l * 16 + 8) = hi;
    }
}

// ===========================================================================
// conv2 edge-MLP: layer-1 C-init gathers REPLACED by MFMA over gathered h1.
// A1 k-map (full K=32): q0 = h1[src][0:8], q1 = h1[src][8:16],
//                       q2 = h1[dst][0:8], q3 = h1[dst][8:16]
//   -> ONE 16 B gather per lane (vs 32 tiny gathers before).
// A2 k-map: q0 = eah (rows 32:39 of W1).
// C = mfma(A1, W1[0:32], mfma(A2, W1[32:40], b1))
// ===========================================================================
__global__ __launch_bounds__(256) void edge_mlp2(
    const _Float16* __restrict__ h1,           // [N,16] fp16
    const int*   __restrict__ ei,
    const _Float16* __restrict__ eah,
    const int*   __restrict__ pos,
    const unsigned short* __restrict__ r,
    const float* __restrict__ w1, const float* __restrict__ b1v, // [40,16],[16]
    const float* __restrict__ w2, const float* __restrict__ b2,  // 16x16
    _Float16* __restrict__ m2h, int E)
{
    __shared__ _Float16 itm[4][4][16][24];
    int tid = threadIdx.x;
    int w = tid >> 6, lane = tid & 63;
    int e16 = lane & 15, q = lane >> 4;
    int ebase = (blockIdx.x * 4 + w) << 6;
    if (ebase >= E) return;
    int e = ebase + lane;

    int s_l = 0, d_l = 0, p_l = 0;
    if (e < E) {
        s_l = ei[e];
        d_l = ei[E + e];
        p_l = pos[(size_t)s_l * NBKT + ((e >> 8) & (NBKT - 1))] + (int)r[e];
    }

    // B fragments: B1 uses ALL 32 k-rows of W1; B2e only rows 32:39 (q0)
    half8 B1, B2e, BL2;
    #pragma unroll
    for (int j = 0; j < 8; ++j) {
        B1[j] = (_Float16)w1[(8 * q + j) * 16 + e16];
        B2e[j] = (_Float16)0.f; BL2[j] = (_Float16)0.f;
    }
    if (q == 0) {
        #pragma unroll
        for (int j = 0; j < 8; ++j)
            B2e[j] = (_Float16)w1[(32 + j) * 16 + e16];
    }
    if (q < 2) {
        #pragma unroll
        for (int j = 0; j < 8; ++j)
            BL2[j] = (_Float16)w2[(8 * q + j) * 16 + e16];
    }
    float b1c = b1v[e16], b2c = b2[e16];

    // A2 (edge attrs, coalesced)
    half8 A2[4];
    #pragma unroll
    for (int t = 0; t < 4; ++t) {
        half8 a;
        #pragma unroll
        for (int j = 0; j < 8; ++j) a[j] = (_Float16)0.f;
        int et = ebase + 16 * t + e16;
        if (q == 0 && et < E)
            a = *(const half8*)(eah + (size_t)et * 8);
        A2[t] = a;
    }

    // A1 (h1 gathers: one 16 B load per lane per tile)
    half8 A1[4];
    #pragma unroll
    for (int t = 0; t < 4; ++t) {
        int st = __shfl(s_l, 16 * t + e16, 64);
        int dt = __shfl(d_l, 16 * t + e16, 64);
        int row = (q < 2) ? st : dt;
        A1[t] = *(const half8*)(h1 + (size_t)row * 16 + 8 * (q & 1));
    }

    floatx4 C[4];
    #pragma unroll
    for (int t = 0; t < 4; ++t) {
        floatx4 c = {b1c, b1c, b1c, b1c};
        c = __builtin_amdgcn_mfma_f32_16x16x32_f16(A2[t], B2e, c, 0, 0, 0);
        C[t] = __builtin_amdgcn_mfma_f32_16x16x32_f16(A1[t], B1, c, 0, 0, 0);
    }
    #pragma unroll
    for (int t = 0; t < 4; ++t)
        #pragma unroll
        for (int i = 0; i < 4; ++i)
            itm[w][t][4 * q + i][e16] = (_Float16)fmaxf(C[t][i], 0.0f);
    __builtin_amdgcn_wave_barrier();

    half8 A2L[4];
    #pragma unroll
    for (int t = 0; t < 4; ++t) {
        half8 a;
        #pragma unroll
        for (int j = 0; j < 8; ++j) a[j] = (_Float16)0.f;
        if (q < 2) a = *(const half8*)&itm[w][t][e16][8 * q];
        A2L[t] = a;
    }
    __builtin_amdgcn_wave_barrier();
    floatx4 C2[4];
    #pragma unroll
    for (int t = 0; t < 4; ++t) {
        floatx4 c = {b2c, b2c, b2c, b2c};
        C2[t] = __builtin_amdgcn_mfma_f32_16x16x32_f16(A2L[t], BL2, c, 0, 0, 0);
    }
    #pragma unroll
    for (int t = 0; t < 4; ++t)
        #pragma unroll
        for (int i = 0; i < 4; ++i)
            itm[w][t][4 * q + i][e16] = (_Float16)C2[t][i];
    __builtin_amdgcn_wave_barrier();

    if (e < E) {
        half8 lo = *(const half8*)&itm[w][q][e16][0];
        half8 hi = *(const half8*)&itm[w][q][e16][8];
        *(half8*)(m2h + (size_t)p_l * 16)     = lo;
        *(half8*)(m2h + (size_t)p_l * 16 + 8) = hi;
    }
}

// ===========================================================================
// Streaming segment-max (8 lanes/node), packed fp16 max (v_pk_max_f16).
// Segment n spans pos[n*NBKT] .. pos[(n+1)*NBKT].  acc init 0 == outer ReLU
// clamp + PyG empty fill (messages ReLU'd per reference semantics).
// segmax1 emits h1[N,16] fp16.  segmax2 fuses the dense head.
// ===========================================================================
__global__ __launch_bounds__(256) void segmax1_h(
    const _Float16* __restrict__ m2h, const int* __restrict__ pos,
    unsigned int* __restrict__ h1u,     // [N,8] u32 (=16 fp16)
    int N, int E)
{
    int tid = threadIdx.x;
    int n = blockIdx.x * 32 + (tid >> 3);
    if (n >= N) return;
    int g = tid & 7;
    int start = pos[(size_t)n * NBKT];
    int end = (n + 1 < N) ? pos[(size_t)(n + 1) * NBKT] : E;

    half8 a0, a1;
    #pragma unroll
    for (int j = 0; j < 8; ++j) { a0[j] = (_Float16)0.f; a1[j] = (_Float16)0.f; }

    for (int k = start + g; k < end; k += 8) {
        half8 v0 = *(const half8*)(m2h + (size_t)k * 16);
        half8 v1 = *(const half8*)(m2h + (size_t)k * 16 + 8);
        a0 = hmax8(a0, v0);
        a1 = hmax8(a1, v1);
    }
    #pragma unroll
    for (int mask = 1; mask < 8; mask <<= 1) {
        H8 x0, x1, y0, y1;
        x0.h = a0; x1.h = a1;
        #pragma unroll
        for (int j = 0; j < 4; ++j) {
            y0.u[j] = __shfl_xor(x0.u[j], mask, 64);
            y1.u[j] = __shfl_xor(x1.u[j], mask, 64);
        }
        a0 = hmax8(a0, y0.h);
        a1 = hmax8(a1, y1.h);
    }
    H8 U0, U1; U0.h = a0; U1.h = a1;
    unsigned int word = (g < 4) ? U0.u[g & 3] : U1.u[g & 3];
    h1u[(size_t)n * 8 + g] = word;
}

__global__ __launch_bounds__(256) void segmax2_head(
    const _Float16* __restrict__ m2h, const int* __restrict__ pos,
    const float* __restrict__ l1w, const float* __restrict__ l1b,
    const float* __restrict__ l2w, const float* __restrict__ l2b,
    float* __restrict__ out, int N, int E)
{
    int tid = threadIdx.x;
    int n = blockIdx.x * 32 + (tid >> 3);
    if (n >= N) return;
    int g = tid & 7;
    int start = pos[(size_t)n * NBKT];
    int end = (n + 1 < N) ? pos[(size_t)(n + 1) * NBKT] : E;

    half8 a0, a1;
    #pragma unroll
    for (int j = 0; j < 8; ++j) { a0[j] = (_Float16)0.f; a1[j] = (_Float16)0.f; }

    for (int k = start + g; k < end; k += 8) {
        half8 v0 = *(const half8*)(m2h + (size_t)k * 16);
        half8 v1 = *(const half8*)(m2h + (size_t)k * 16 + 8);
        a0 = hmax8(a0, v0);
        a1 = hmax8(a1, v1);
    }
    #pragma unroll
    for (int mask = 1; mask < 8; mask <<= 1) {
        H8 x0, x1, y0, y1;
        x0.h = a0; x1.h = a1;
        #pragma unroll
        for (int j = 0; j < 4; ++j) {
            y0.u[j] = __shfl_xor(x0.u[j], mask, 64);
            y1.u[j] = __shfl_xor(x1.u[j], mask, 64);
        }
        a0 = hmax8(a0, y0.h);
        a1 = hmax8(a1, y1.h);
    }

    float acc[16];
    #pragma unroll
    for (int j = 0; j < 8; ++j) { acc[j] = (float)a0[j]; acc[8 + j] = (float)a1[j]; }

    float t2[16];
    #pragma unroll
    for (int j = 0; j < 16; ++j) t2[j] = l1b[j];
    #pragma unroll
    for (int kk = 0; kk < 16; ++kk) {
        float ak = acc[kk];
        #pragma unroll
        for (int j = 0; j < 16; ++j) t2[j] = fmaf(ak, l1w[kk * 16 + j], t2[j]);
    }
    float r2 = l2b[0];
    #pragma unroll
    for (int j = 0; j < 16; ++j) r2 = fmaf(fmaxf(t2[j], 0.0f), l2w[j], r2);
    if (g == 0) out[n] = r2;
}

// ===========================================================================
extern "C" void kernel_launch(void* const* d_in, const int* in_sizes, int n_in,
                              void* d_out, int out_size, void* d_ws, size_t ws_size,
                              hipStream_t stream)
{
    const float* x     = (const float*)d_in[0];
    const int*   ei    = (const int*)  d_in[1];
    const float* ea    = (const float*)d_in[2];
    const float* c1_w1 = (const float*)d_in[3];
    const float* c1_b1 = (const float*)d_in[4];
    const float* c1_w2 = (const float*)d_in[5];
    const float* c1_b2 = (const float*)d_in[6];
    const float* c2_w1 = (const float*)d_in[7];
    const float* c2_b1 = (const float*)d_in[8];
    const float* c2_w2 = (const float*)d_in[9];
    const float* c2_b2 = (const float*)d_in[10];
    const float* l1_w  = (const float*)d_in[11];
    const float* l1_b  = (const float*)d_in[12];
    const float* l2_w  = (const float*)d_in[13];
    const float* l2_b  = (const float*)d_in[14];
    float* out = (float*)d_out;

    const int N = in_sizes[0] / 4;   // 100000
    const int E = in_sizes[2] / 8;   // 1600000
    const int M = N * NBKT;
    const int nch = (M + CHUNK - 1) / CHUNK;

    const int BLK = 256;
    const int egrid = (E + BLK - 1) / BLK;
    const int ggrid = (N + 31) / 32;
    const int ntiles64 = (E + 63) >> 6;
    const int mgrid = (ntiles64 + 3) / 4;

    size_t szPos = ((size_t)M * 4 + 15) & ~(size_t)15;   // 3.2 MB
    size_t szR   = ((size_t)E * 2 + 15) & ~(size_t)15;   // 3.2 MB
    size_t szXh  = ((size_t)N * 8 + 15) & ~(size_t)15;   // 0.8 MB
    size_t szH1  = ((size_t)N * 32 + 15) & ~(size_t)15;  // 3.2 MB
    size_t szEah = (size_t)E * 16;                       // 25.6 MB
    size_t szM2h = (size_t)E * 32;                       // 51.2 MB

    size_t pos_off = 0;
    size_t r_off   = pos_off + szPos;
    size_t xh_off  = r_off   + szR;
    size_t h1_off  = xh_off  + szXh;
    size_t eah_off = h1_off  + szH1;
    size_t m2h_off = eah_off + szEah;
    // overlays inside m2h (dead until edge_mlp1 writes it):
    size_t deg_off = m2h_off;
    size_t cs_off  = deg_off + szPos;
    size_t cf_off  = cs_off + 16384;

    int*            pos  = (int*)  ((char*)d_ws + pos_off);
    unsigned short* r    = (unsigned short*)((char*)d_ws + r_off);
    _Float16*       xh   = (_Float16*)((char*)d_ws + xh_off);
    _Float16*       h1   = (_Float16*)((char*)d_ws + h1_off);
    _Float16*       eah  = (_Float16*)((char*)d_ws + eah_off);
    _Float16*       m2h  = (_Float16*)((char*)d_ws + m2h_off);
    int*            deg  = (int*)  ((char*)d_ws + deg_off);
    int*            csum = (int*)  ((char*)d_ws + cs_off);
    int*            coff = (int*)  ((char*)d_ws + cf_off);

    hipMemsetAsync(deg, 0, (size_t)M * 4, stream);
    rank_cvt<<<egrid, BLK, 0, stream>>>(ei, ea, x, deg, r, eah, xh, E, N);
    scan_chunk_sums<<<nch, BLK, 0, stream>>>(deg, csum, M);
    scan_chunk_off<<<1, 256, 0, stream>>>(csum, coff, nch);
    scan_within_excl<<<nch, BLK, 0, stream>>>(deg, pos, coff, M);
    edge_mlp1<<<mgrid, BLK, 0, stream>>>(xh, ei, eah, pos, r,
                                         c1_w1, c1_b1, c1_w2, c1_b2, m2h, E);
    segmax1_h<<<ggrid, BLK, 0, stream>>>(m2h, pos, (unsigned int*)h1, N, E);
    edge_mlp2<<<mgrid, BLK, 0, stream>>>(h1, ei, eah, pos, r,
                                         c2_w1, c2_b1, c2_w2, c2_b2, m2h, E);
    segmax2_head<<<ggrid, BLK, 0, stream>>>(m2h, pos, l1_w, l1_b, l2_w, l2_b,
                                            out, N, E);
}

// Round 7
// 348.188 us; speedup vs baseline: 1.2485x; 1.0138x over previous
//
#include <hip/hip_runtime.h>
#include <hip/hip_fp16.h>

#define CHUNK 1024
#define NBKT 8     // per-node atomic-counter buckets

typedef _Float16 half8 __attribute__((ext_vector_type(8)));
typedef _Float16 half4 __attribute__((ext_vector_type(4)));
typedef float floatx4 __attribute__((ext_vector_type(4)));

union H8 { half8 h; unsigned int u[4]; };

__device__ __forceinline__ half8 hmax8(half8 a, half8 b) {
#if __has_builtin(__builtin_elementwise_max)
    return __builtin_elementwise_max(a, b);
#else
    half8 r;
    #pragma unroll
    for (int j = 0; j < 8; ++j) r[j] = a[j] > b[j] ? a[j] : b[j];
    return r;
#endif
}

// ===========================================================================
// rank (atomicAdd over [N][NBKT] counters) + ea->fp16 + x->fp16, one pass.
// ===========================================================================
__global__ __launch_bounds__(256) void rank_cvt(
    const int* __restrict__ ei, const float* __restrict__ ea,
    const float* __restrict__ x,
    int* __restrict__ deg, unsigned short* __restrict__ r,
    _Float16* __restrict__ eah, _Float16* __restrict__ xh,
    int E, int N)
{
    int e = blockIdx.x * 256 + threadIdx.x;
    if (e >= E) return;
    r[e] = (unsigned short)atomicAdd(&deg[(size_t)ei[e] * NBKT + ((e >> 8) & (NBKT - 1))], 1);
    float4 a0 = *(const float4*)(ea + (size_t)e * 8);
    float4 a1 = *(const float4*)(ea + (size_t)e * 8 + 4);
    half8 h;
    h[0] = (_Float16)a0.x; h[1] = (_Float16)a0.y;
    h[2] = (_Float16)a0.z; h[3] = (_Float16)a0.w;
    h[4] = (_Float16)a1.x; h[5] = (_Float16)a1.y;
    h[6] = (_Float16)a1.z; h[7] = (_Float16)a1.w;
    *(half8*)(eah + (size_t)e * 8) = h;
    if (e < N) {
        float4 xv = *(const float4*)(x + (size_t)e * 4);
        half4 hx;
        hx[0] = (_Float16)xv.x; hx[1] = (_Float16)xv.y;
        hx[2] = (_Float16)xv.z; hx[3] = (_Float16)xv.w;
        *(half4*)(xh + (size_t)e * 4) = hx;
    }
}

__global__ __launch_bounds__(256) void scan_chunk_sums(
    const int* __restrict__ v, int* __restrict__ csum, int N)
{
    __shared__ int s[256];
    int base = blockIdx.x * CHUNK;
    int t = threadIdx.x;
    int acc = 0;
    #pragma unroll
    for (int i = 0; i < CHUNK / 256; ++i) {
        int idx = base + t + i * 256;
        if (idx < N) acc += v[idx];
    }
    s[t] = acc; __syncthreads();
    for (int o = 128; o > 0; o >>= 1) {
        if (t < o) s[t] += s[t + o];
        __syncthreads();
    }
    if (t == 0) csum[blockIdx.x] = s[0];
}

__global__ __launch_bounds__(256) void scan_chunk_off(
    const int* __restrict__ csum, int* __restrict__ coff, int nch)
{
    __shared__ int s[256];
    __shared__ int carry;
    int t = threadIdx.x;
    if (t == 0) carry = 0;
    __syncthreads();
    for (int base = 0; base < nch; base += 256) {
        int v = (base + t < nch) ? csum[base + t] : 0;
        s[t] = v; __syncthreads();
        for (int o = 1; o < 256; o <<= 1) {
            int add = (t >= o) ? s[t - o] : 0;
            __syncthreads();
            s[t] += add;
            __syncthreads();
        }
        int excl = carry + (t > 0 ? s[t - 1] : 0);
        if (base + t < nch) coff[base + t] = excl;
        __syncthreads();
        if (t == 0) carry += s[255];
        __syncthreads();
    }
}

__global__ __launch_bounds__(256) void scan_within_excl(
    const int* __restrict__ deg, int* __restrict__ pos,
    const int* __restrict__ coff, int N)
{
    __shared__ int s[256];
    int t = threadIdx.x;
    int base = blockIdx.x * CHUNK + t * 4;
    int v0 = 0, v1 = 0, v2 = 0, v3 = 0;
    if (base + 0 < N) v0 = deg[base + 0];
    if (base + 1 < N) v1 = deg[base + 1];
    if (base + 2 < N) v2 = deg[base + 2];
    if (base + 3 < N) v3 = deg[base + 3];
    s[t] = v0 + v1 + v2 + v3;
    __syncthreads();
    for (int o = 1; o < 256; o <<= 1) {
        int add = (t >= o) ? s[t - o] : 0;
        __syncthreads();
        s[t] += add;
        __syncthreads();
    }
    int run = coff[blockIdx.x] + (t > 0 ? s[t - 1] : 0);
    if (base + 0 < N) pos[base + 0] = run; run += v0;
    if (base + 1 < N) pos[base + 1] = run; run += v1;
    if (base + 2 < N) pos[base + 2] = run; run += v2;
    if (base + 3 < N) pos[base + 3] = run;
}

// ===========================================================================
// conv1 edge-MLP: TWO 64-edge macro-tiles per wave (8 x 16x16 MFMA tiles)
// for 2x ILP per dependency hop; per-wave fixed costs amortized.
//   16x16x32 layouts: A[m=lane&15][k=8q+j], B[k=8q+j][n=lane&15],
//   C/D: col=lane&15, row=4q+reg.
// A k-map: q0 j0-3 = xh[src], j4-7 = xh[dst]; q1 j0-7 = eah; q2/q3 zero.
// CSR slot: pos[src*NBKT+(e>>8)&7] + r[e]; 32 B scattered store.
// ===========================================================================
__global__ __launch_bounds__(256) void edge_mlp1(
    const _Float16* __restrict__ xh,      // [N,4] fp16
    const int*   __restrict__ ei,         // [2,E]
    const _Float16* __restrict__ eah,     // [E,8] fp16
    const int*   __restrict__ pos,        // [N*NBKT] exclusive scan
    const unsigned short* __restrict__ r,
    const float* __restrict__ w1, const float* __restrict__ b1,  // 16x16
    const float* __restrict__ w2, const float* __restrict__ b2,  // 16x16
    _Float16* __restrict__ m2h,           // [E,16] CSR-ordered out
    int E)
{
    __shared__ _Float16 itm[4][8][16][24];
    int tid = threadIdx.x;
    int w = tid >> 6, lane = tid & 63;
    int e16 = lane & 15, q = lane >> 4;
    int ebase = (blockIdx.x * 4 + w) << 7;    // 128 edges per wave
    if (ebase >= E) return;
    int e0 = ebase + lane;
    int e1 = ebase + 64 + lane;

    int s0 = 0, d0 = 0, p0 = 0, s1 = 0, d1 = 0, p1 = 0;
    if (e0 < E) {
        s0 = ei[e0]; d0 = ei[E + e0];
        p0 = pos[(size_t)s0 * NBKT + ((e0 >> 8) & (NBKT - 1))] + (int)r[e0];
    }
    if (e1 < E) {
        s1 = ei[e1]; d1 = ei[E + e1];
        p1 = pos[(size_t)s1 * NBKT + ((e1 >> 8) & (NBKT - 1))] + (int)r[e1];
    }

    half8 B1, B2;
    #pragma unroll
    for (int j = 0; j < 8; ++j) { B1[j] = (_Float16)0.f; B2[j] = (_Float16)0.f; }
    if (q < 2) {
        #pragma unroll
        for (int j = 0; j < 8; ++j) {
            B1[j] = (_Float16)w1[(8 * q + j) * 16 + e16];
            B2[j] = (_Float16)w2[(8 * q + j) * 16 + e16];
        }
    }
    float b1c = b1[e16], b2c = b2[e16];

    half8 A[8];
    #pragma unroll
    for (int t = 0; t < 8; ++t) {
        int tt = t & 3;
        int st = (t < 4) ? __shfl(s0, 16 * tt + e16, 64) : __shfl(s1, 16 * tt + e16, 64);
        int dt = (t < 4) ? __shfl(d0, 16 * tt + e16, 64) : __shfl(d1, 16 * tt + e16, 64);
        half8 a;
        #pragma unroll
        for (int j = 0; j < 8; ++j) a[j] = (_Float16)0.f;
        int et = ebase + 16 * t + e16;
        if (q == 0 && et < E) {
            half4 hs = *(const half4*)(xh + (size_t)st * 4);
            half4 hd = *(const half4*)(xh + (size_t)dt * 4);
            a[0] = hs[0]; a[1] = hs[1]; a[2] = hs[2]; a[3] = hs[3];
            a[4] = hd[0]; a[5] = hd[1]; a[6] = hd[2]; a[7] = hd[3];
        } else if (q == 1 && et < E) {
            a = *(const half8*)(eah + (size_t)et * 8);
        }
        A[t] = a;
    }

    floatx4 C[8];
    #pragma unroll
    for (int t = 0; t < 8; ++t) {
        floatx4 c = {b1c, b1c, b1c, b1c};
        C[t] = __builtin_amdgcn_mfma_f32_16x16x32_f16(A[t], B1, c, 0, 0, 0);
    }
    #pragma unroll
    for (int t = 0; t < 8; ++t)
        #pragma unroll
        for (int i = 0; i < 4; ++i)
            itm[w][t][4 * q + i][e16] = (_Float16)fmaxf(C[t][i], 0.0f);
    __builtin_amdgcn_wave_barrier();

    half8 A2[8];
    #pragma unroll
    for (int t = 0; t < 8; ++t) {
        half8 a;
        #pragma unroll
        for (int j = 0; j < 8; ++j) a[j] = (_Float16)0.f;
        if (q < 2) a = *(const half8*)&itm[w][t][e16][8 * q];
        A2[t] = a;
    }
    __builtin_amdgcn_wave_barrier();
    floatx4 C2[8];
    #pragma unroll
    for (int t = 0; t < 8; ++t) {
        floatx4 c = {b2c, b2c, b2c, b2c};
        C2[t] = __builtin_amdgcn_mfma_f32_16x16x32_f16(A2[t], B2, c, 0, 0, 0);
    }
    #pragma unroll
    for (int t = 0; t < 8; ++t)
        #pragma unroll
        for (int i = 0; i < 4; ++i)
            itm[w][t][4 * q + i][e16] = (_Float16)C2[t][i];
    __builtin_amdgcn_wave_barrier();

    if (e0 < E) {
        half8 lo = *(const half8*)&itm[w][q][e16][0];
        half8 hi = *(const half8*)&itm[w][q][e16][8];
        *(half8*)(m2h + (size_t)p0 * 16)     = lo;
        *(half8*)(m2h + (size_t)p0 * 16 + 8) = hi;
    }
    if (e1 < E) {
        half8 lo = *(const half8*)&itm[w][q + 4][e16][0];
        half8 hi = *(const half8*)&itm[w][q + 4][e16][8];
        *(half8*)(m2h + (size_t)p1 * 16)     = lo;
        *(half8*)(m2h + (size_t)p1 * 16 + 8) = hi;
    }
}

// ===========================================================================
// conv2 edge-MLP: TWO quads per wave; layer-1 C-init via MFMA over gathered
// h1 (one 16 B gather per lane per tile).
// A1 k-map (K=32): q0 = h1[src][0:8], q1 = h1[src][8:16],
//                  q2 = h1[dst][0:8], q3 = h1[dst][8:16]
// A2 k-map: q0 = eah (rows 32:40 of W1).
// C = mfma(A1, W1[0:32], mfma(A2, W1[32:40], b1))
// ===========================================================================
__global__ __launch_bounds__(256) void edge_mlp2(
    const _Float16* __restrict__ h1,           // [N,16] fp16
    const int*   __restrict__ ei,
    const _Float16* __restrict__ eah,
    const int*   __restrict__ pos,
    const unsigned short* __restrict__ r,
    const float* __restrict__ w1, const float* __restrict__ b1v, // [40,16],[16]
    const float* __restrict__ w2, const float* __restrict__ b2,  // 16x16
    _Float16* __restrict__ m2h, int E)
{
    __shared__ _Float16 itm[4][8][16][24];
    int tid = threadIdx.x;
    int w = tid >> 6, lane = tid & 63;
    int e16 = lane & 15, q = lane >> 4;
    int ebase = (blockIdx.x * 4 + w) << 7;
    if (ebase >= E) return;
    int e0 = ebase + lane;
    int e1 = ebase + 64 + lane;

    int s0 = 0, d0 = 0, p0 = 0, s1 = 0, d1 = 0, p1 = 0;
    if (e0 < E) {
        s0 = ei[e0]; d0 = ei[E + e0];
        p0 = pos[(size_t)s0 * NBKT + ((e0 >> 8) & (NBKT - 1))] + (int)r[e0];
    }
    if (e1 < E) {
        s1 = ei[e1]; d1 = ei[E + e1];
        p1 = pos[(size_t)s1 * NBKT + ((e1 >> 8) & (NBKT - 1))] + (int)r[e1];
    }

    half8 B1, B2e, BL2;
    #pragma unroll
    for (int j = 0; j < 8; ++j) {
        B1[j] = (_Float16)w1[(8 * q + j) * 16 + e16];
        B2e[j] = (_Float16)0.f; BL2[j] = (_Float16)0.f;
    }
    if (q == 0) {
        #pragma unroll
        for (int j = 0; j < 8; ++j)
            B2e[j] = (_Float16)w1[(32 + j) * 16 + e16];
    }
    if (q < 2) {
        #pragma unroll
        for (int j = 0; j < 8; ++j)
            BL2[j] = (_Float16)w2[(8 * q + j) * 16 + e16];
    }
    float b1c = b1v[e16], b2c = b2[e16];

    // A1 (h1 gathers: one 16 B load per lane per tile)
    half8 A1[8];
    #pragma unroll
    for (int t = 0; t < 8; ++t) {
        int tt = t & 3;
        int st = (t < 4) ? __shfl(s0, 16 * tt + e16, 64) : __shfl(s1, 16 * tt + e16, 64);
        int dt = (t < 4) ? __shfl(d0, 16 * tt + e16, 64) : __shfl(d1, 16 * tt + e16, 64);
        int row = (q < 2) ? st : dt;
        A1[t] = *(const half8*)(h1 + (size_t)row * 16 + 8 * (q & 1));
    }

    floatx4 C[8];
    #pragma unroll
    for (int t = 0; t < 8; ++t) {
        half8 a2;
        #pragma unroll
        for (int j = 0; j < 8; ++j) a2[j] = (_Float16)0.f;
        int et = ebase + 16 * t + e16;
        if (q == 0 && et < E)
            a2 = *(const half8*)(eah + (size_t)et * 8);
        floatx4 c = {b1c, b1c, b1c, b1c};
        c = __builtin_amdgcn_mfma_f32_16x16x32_f16(a2, B2e, c, 0, 0, 0);
        C[t] = __builtin_amdgcn_mfma_f32_16x16x32_f16(A1[t], B1, c, 0, 0, 0);
    }
    #pragma unroll
    for (int t = 0; t < 8; ++t)
        #pragma unroll
        for (int i = 0; i < 4; ++i)
            itm[w][t][4 * q + i][e16] = (_Float16)fmaxf(C[t][i], 0.0f);
    __builtin_amdgcn_wave_barrier();

    half8 A2L[8];
    #pragma unroll
    for (int t = 0; t < 8; ++t) {
        half8 a;
        #pragma unroll
        for (int j = 0; j < 8; ++j) a[j] = (_Float16)0.f;
        if (q < 2) a = *(const half8*)&itm[w][t][e16][8 * q];
        A2L[t] = a;
    }
    __builtin_amdgcn_wave_barrier();
    floatx4 C2[8];
    #pragma unroll
    for (int t = 0; t < 8; ++t) {
        floatx4 c = {b2c, b2c, b2c, b2c};
        C2[t] = __builtin_amdgcn_mfma_f32_16x16x32_f16(A2L[t], BL2, c, 0, 0, 0);
    }
    #pragma unroll
    for (int t = 0; t < 8; ++t)
        #pragma unroll
        for (int i = 0; i < 4; ++i)
            itm[w][t][4 * q + i][e16] = (_Float16)C2[t][i];
    __builtin_amdgcn_wave_barrier();

    if (e0 < E) {
        half8 lo = *(const half8*)&itm[w][q][e16][0];
        half8 hi = *(const half8*)&itm[w][q][e16][8];
        *(half8*)(m2h + (size_t)p0 * 16)     = lo;
        *(half8*)(m2h + (size_t)p0 * 16 + 8) = hi;
    }
    if (e1 < E) {
        half8 lo = *(const half8*)&itm[w][q + 4][e16][0];
        half8 hi = *(const half8*)&itm[w][q + 4][e16][8];
        *(half8*)(m2h + (size_t)p1 * 16)     = lo;
        *(half8*)(m2h + (size_t)p1 * 16 + 8) = hi;
    }
}

// ===========================================================================
// Streaming segment-max (8 lanes/node), packed fp16 max.
// Segment n spans pos[n*NBKT] .. pos[(n+1)*NBKT].  acc init 0 == outer ReLU
// clamp + PyG empty fill.  segmax1 emits h1[N,16] fp16; segmax2 fuses head.
// ===========================================================================
__global__ __launch_bounds__(256) void segmax1_h(
    const _Float16* __restrict__ m2h, const int* __restrict__ pos,
    unsigned int* __restrict__ h1u,     // [N,8] u32 (=16 fp16)
    int N, int E)
{
    int tid = threadIdx.x;
    int n = blockIdx.x * 32 + (tid >> 3);
    if (n >= N) return;
    int g = tid & 7;
    int start = pos[(size_t)n * NBKT];
    int end = (n + 1 < N) ? pos[(size_t)(n + 1) * NBKT] : E;

    half8 a0, a1;
    #pragma unroll
    for (int j = 0; j < 8; ++j) { a0[j] = (_Float16)0.f; a1[j] = (_Float16)0.f; }

    for (int k = start + g; k < end; k += 8) {
        half8 v0 = *(const half8*)(m2h + (size_t)k * 16);
        half8 v1 = *(const half8*)(m2h + (size_t)k * 16 + 8);
        a0 = hmax8(a0, v0);
        a1 = hmax8(a1, v1);
    }
    #pragma unroll
    for (int mask = 1; mask < 8; mask <<= 1) {
        H8 x0, x1, y0, y1;
        x0.h = a0; x1.h = a1;
        #pragma unroll
        for (int j = 0; j < 4; ++j) {
            y0.u[j] = __shfl_xor(x0.u[j], mask, 64);
            y1.u[j] = __shfl_xor(x1.u[j], mask, 64);
        }
        a0 = hmax8(a0, y0.h);
        a1 = hmax8(a1, y1.h);
    }
    H8 U0, U1; U0.h = a0; U1.h = a1;
    unsigned int word = (g < 4) ? U0.u[g & 3] : U1.u[g & 3];
    h1u[(size_t)n * 8 + g] = word;
}

__global__ __launch_bounds__(256) void segmax2_head(
    const _Float16* __restrict__ m2h, const int* __restrict__ pos,
    const float* __restrict__ l1w, const float* __restrict__ l1b,
    const float* __restrict__ l2w, const float* __restrict__ l2b,
    float* __restrict__ out, int N, int E)
{
    int tid = threadIdx.x;
    int n = blockIdx.x * 32 + (tid >> 3);
    if (n >= N) return;
    int g = tid & 7;
    int start = pos[(size_t)n * NBKT];
    int end = (n + 1 < N) ? pos[(size_t)(n + 1) * NBKT] : E;

    half8 a0, a1;
    #pragma unroll
    for (int j = 0; j < 8; ++j) { a0[j] = (_Float16)0.f; a1[j] = (_Float16)0.f; }

    for (int k = start + g; k < end; k += 8) {
        half8 v0 = *(const half8*)(m2h + (size_t)k * 16);
        half8 v1 = *(const half8*)(m2h + (size_t)k * 16 + 8);
        a0 = hmax8(a0, v0);
        a1 = hmax8(a1, v1);
    }
    #pragma unroll
    for (int mask = 1; mask < 8; mask <<= 1) {
        H8 x0, x1, y0, y1;
        x0.h = a0; x1.h = a1;
        #pragma unroll
        for (int j = 0; j < 4; ++j) {
            y0.u[j] = __shfl_xor(x0.u[j], mask, 64);
            y1.u[j] = __shfl_xor(x1.u[j], mask, 64);
        }
        a0 = hmax8(a0, y0.h);
        a1 = hmax8(a1, y1.h);
    }

    float acc[16];
    #pragma unroll
    for (int j = 0; j < 8; ++j) { acc[j] = (float)a0[j]; acc[8 + j] = (float)a1[j]; }

    float t2[16];
    #pragma unroll
    for (int j = 0; j < 16; ++j) t2[j] = l1b[j];
    #pragma unroll
    for (int kk = 0; kk < 16; ++kk) {
        float ak = acc[kk];
        #pragma unroll
        for (int j = 0; j < 16; ++j) t2[j] = fmaf(ak, l1w[kk * 16 + j], t2[j]);
    }
    float r2 = l2b[0];
    #pragma unroll
    for (int j = 0; j < 16; ++j) r2 = fmaf(fmaxf(t2[j], 0.0f), l2w[j], r2);
    if (g == 0) out[n] = r2;
}

// ===========================================================================
extern "C" void kernel_launch(void* const* d_in, const int* in_sizes, int n_in,
                              void* d_out, int out_size, void* d_ws, size_t ws_size,
                              hipStream_t stream)
{
    const float* x     = (const float*)d_in[0];
    const int*   ei    = (const int*)  d_in[1];
    const float* ea    = (const float*)d_in[2];
    const float* c1_w1 = (const float*)d_in[3];
    const float* c1_b1 = (const float*)d_in[4];
    const float* c1_w2 = (const float*)d_in[5];
    const float* c1_b2 = (const float*)d_in[6];
    const float* c2_w1 = (const float*)d_in[7];
    const float* c2_b1 = (const float*)d_in[8];
    const float* c2_w2 = (const float*)d_in[9];
    const float* c2_b2 = (const float*)d_in[10];
    const float* l1_w  = (const float*)d_in[11];
    const float* l1_b  = (const float*)d_in[12];
    const float* l2_w  = (const float*)d_in[13];
    const float* l2_b  = (const float*)d_in[14];
    float* out = (float*)d_out;

    const int N = in_sizes[0] / 4;   // 100000
    const int E = in_sizes[2] / 8;   // 1600000
    const int M = N * NBKT;
    const int nch = (M + CHUNK - 1) / CHUNK;

    const int BLK = 256;
    const int egrid = (E + BLK - 1) / BLK;
    const int ggrid = (N + 31) / 32;
    const int mgrid = (E + 511) / 512;   // 512 edges per block (128/wave)

    size_t szPos = ((size_t)M * 4 + 15) & ~(size_t)15;   // 3.2 MB
    size_t szR   = ((size_t)E * 2 + 15) & ~(size_t)15;   // 3.2 MB
    size_t szXh  = ((size_t)N * 8 + 15) & ~(size_t)15;   // 0.8 MB
    size_t szH1  = ((size_t)N * 32 + 15) & ~(size_t)15;  // 3.2 MB
    size_t szEah = (size_t)E * 16;                       // 25.6 MB
    size_t szM2h = (size_t)E * 32;                       // 51.2 MB

    size_t pos_off = 0;
    size_t r_off   = pos_off + szPos;
    size_t xh_off  = r_off   + szR;
    size_t h1_off  = xh_off  + szXh;
    size_t eah_off = h1_off  + szH1;
    size_t m2h_off = eah_off + szEah;
    // overlays inside m2h (dead until edge_mlp1 writes it):
    size_t deg_off = m2h_off;
    size_t cs_off  = deg_off + szPos;
    size_t cf_off  = cs_off + 16384;

    int*            pos  = (int*)  ((char*)d_ws + pos_off);
    unsigned short* r    = (unsigned short*)((char*)d_ws + r_off);
    _Float16*       xh   = (_Float16*)((char*)d_ws + xh_off);
    _Float16*       h1   = (_Float16*)((char*)d_ws + h1_off);
    _Float16*       eah  = (_Float16*)((char*)d_ws + eah_off);
    _Float16*       m2h  = (_Float16*)((char*)d_ws + m2h_off);
    int*            deg  = (int*)  ((char*)d_ws + deg_off);
    int*            csum = (int*)  ((char*)d_ws + cs_off);
    int*            coff = (int*)  ((char*)d_ws + cf_off);

    hipMemsetAsync(deg, 0, (size_t)M * 4, stream);
    rank_cvt<<<egrid, BLK, 0, stream>>>(ei, ea, x, deg, r, eah, xh, E, N);
    scan_chunk_sums<<<nch, BLK, 0, stream>>>(deg, csum, M);
    scan_chunk_off<<<1, 256, 0, stream>>>(csum, coff, nch);
    scan_within_excl<<<nch, BLK, 0, stream>>>(deg, pos, coff, M);
    edge_mlp1<<<mgrid, BLK, 0, stream>>>(xh, ei, eah, pos, r,
                                         c1_w1, c1_b1, c1_w2, c1_b2, m2h, E);
    segmax1_h<<<ggrid, BLK, 0, stream>>>(m2h, pos, (unsigned int*)h1, N, E);
    edge_mlp2<<<mgrid, BLK, 0, stream>>>(h1, ei, eah, pos, r,
                                         c2_w1, c2_b1, c2_w2, c2_b2, m2h, E);
    segmax2_head<<<ggrid, BLK, 0, stream>>>(m2h, pos, l1_w, l1_b, l2_w, l2_b,
                                            out, N, E);
}

// Round 8
// 345.602 us; speedup vs baseline: 1.2578x; 1.0075x over previous
//
#include <hip/hip_runtime.h>
#include <hip/hip_fp16.h>

#define CHUNK 1024
#define RECB 24    // packed CSR record: {int src, int dst, 8x fp16 attr}

typedef _Float16 half8 __attribute__((ext_vector_type(8)));
typedef _Float16 half4 __attribute__((ext_vector_type(4)));
typedef float floatx4 __attribute__((ext_vector_type(4)));

union H8 { half8 h; unsigned int u[4]; };

__device__ __forceinline__ half8 hmax8(half8 a, half8 b) {
#if __has_builtin(__builtin_elementwise_max)
    return __builtin_elementwise_max(a, b);
#else
    half8 r;
    #pragma unroll
    for (int j = 0; j < 8; ++j) r[j] = a[j] > b[j] ? a[j] : b[j];
    return r;
#endif
}

__device__ __forceinline__ unsigned int pack2f(float a, float b) {
    __half2 h = __floats2half2_rn(a, b);
    return *(unsigned int*)&h;
}

__device__ __forceinline__ half8 load_attr(const char* __restrict__ rec, int et) {
    union { unsigned int u[4]; half8 h; } cv;
    uint2 lo = *(const uint2*)(rec + (size_t)et * RECB + 8);
    uint2 hi = *(const uint2*)(rec + (size_t)et * RECB + 16);
    cv.u[0] = lo.x; cv.u[1] = lo.y; cv.u[2] = hi.x; cv.u[3] = hi.y;
    return cv.h;
}

// ===========================================================================
// rank: r[e] = arrival index within src's segment (atomicAdd w/ return;
// ~23G random-atomic/s wall, contention-independent — NBKT removed).
// Also converts x -> fp16 (xh).
// ===========================================================================
__global__ __launch_bounds__(256) void rank_cvt(
    const int* __restrict__ ei, const float* __restrict__ x,
    int* __restrict__ deg, unsigned short* __restrict__ r,
    _Float16* __restrict__ xh, int E, int N)
{
    int e = blockIdx.x * 256 + threadIdx.x;
    if (e >= E) return;
    r[e] = (unsigned short)atomicAdd(&deg[ei[e]], 1);
    if (e < N) {
        float4 xv = *(const float4*)(x + (size_t)e * 4);
        half4 hx;
        hx[0] = (_Float16)xv.x; hx[1] = (_Float16)xv.y;
        hx[2] = (_Float16)xv.z; hx[3] = (_Float16)xv.w;
        *(half4*)(xh + (size_t)e * 4) = hx;
    }
}

__global__ __launch_bounds__(256) void scan_chunk_sums(
    const int* __restrict__ v, int* __restrict__ csum, int N)
{
    __shared__ int s[256];
    int base = blockIdx.x * CHUNK;
    int t = threadIdx.x;
    int acc = 0;
    #pragma unroll
    for (int i = 0; i < CHUNK / 256; ++i) {
        int idx = base + t + i * 256;
        if (idx < N) acc += v[idx];
    }
    s[t] = acc; __syncthreads();
    for (int o = 128; o > 0; o >>= 1) {
        if (t < o) s[t] += s[t + o];
        __syncthreads();
    }
    if (t == 0) csum[blockIdx.x] = s[0];
}

__global__ __launch_bounds__(256) void scan_chunk_off(
    const int* __restrict__ csum, int* __restrict__ coff, int nch)
{
    __shared__ int s[256];
    __shared__ int carry;
    int t = threadIdx.x;
    if (t == 0) carry = 0;
    __syncthreads();
    for (int base = 0; base < nch; base += 256) {
        int v = (base + t < nch) ? csum[base + t] : 0;
        s[t] = v; __syncthreads();
        for (int o = 1; o < 256; o <<= 1) {
            int add = (t >= o) ? s[t - o] : 0;
            __syncthreads();
            s[t] += add;
            __syncthreads();
        }
        int excl = carry + (t > 0 ? s[t - 1] : 0);
        if (base + t < nch) coff[base + t] = excl;
        __syncthreads();
        if (t == 0) carry += s[255];
        __syncthreads();
    }
}

__global__ __launch_bounds__(256) void scan_within_excl(
    const int* __restrict__ deg, int* __restrict__ pos,
    const int* __restrict__ coff, int N)
{
    __shared__ int s[256];
    int t = threadIdx.x;
    int base = blockIdx.x * CHUNK + t * 4;
    int v0 = 0, v1 = 0, v2 = 0, v3 = 0;
    if (base + 0 < N) v0 = deg[base + 0];
    if (base + 1 < N) v1 = deg[base + 1];
    if (base + 2 < N) v2 = deg[base + 2];
    if (base + 3 < N) v3 = deg[base + 3];
    s[t] = v0 + v1 + v2 + v3;
    __syncthreads();
    for (int o = 1; o < 256; o <<= 1) {
        int add = (t >= o) ? s[t - o] : 0;
        __syncthreads();
        s[t] += add;
        __syncthreads();
    }
    int run = coff[blockIdx.x] + (t > 0 ? s[t - 1] : 0);
    if (base + 0 < N) pos[base + 0] = run; run += v0;
    if (base + 1 < N) pos[base + 1] = run; run += v1;
    if (base + 2 < N) pos[base + 2] = run; run += v2;
    if (base + 3 < N) pos[base + 3] = run;
}

// ===========================================================================
// CSR record scatter — the ONLY bulk random-store pass besides rank.
// rec[p] = {src, dst, attr fp16}, p = pos[src] + r[e].  24 B packed so the
// whole record is 1 line-op, ~2.7 writers/64B line.
// ===========================================================================
__global__ __launch_bounds__(256) void scatter_rec(
    const int* __restrict__ ei, const float* __restrict__ ea,
    const int* __restrict__ pos, const unsigned short* __restrict__ r,
    char* __restrict__ rec, int E)
{
    int e = blockIdx.x * 256 + threadIdx.x;
    if (e >= E) return;
    int s = ei[e];
    int d = ei[E + e];
    int p = pos[s] + (int)r[e];
    float4 a0 = *(const float4*)(ea + (size_t)e * 8);
    float4 a1 = *(const float4*)(ea + (size_t)e * 8 + 4);
    unsigned int h0 = pack2f(a0.x, a0.y), h1 = pack2f(a0.z, a0.w);
    unsigned int h2 = pack2f(a1.x, a1.y), h3 = pack2f(a1.z, a1.w);
    char* b = rec + (size_t)p * RECB;
    *(int2*)b         = make_int2(s, d);
    *(uint2*)(b + 8)  = make_uint2(h0, h1);
    *(uint2*)(b + 16) = make_uint2(h2, h3);
}

// ===========================================================================
// conv1 edge-MLP over CSR-ordered records: ALL streams coalesced, m2h
// written coalesced at the edge's CSR position (= thread index).  TWO
// 64-edge macro-tiles per wave (8 x 16x16 MFMA tiles).
//   16x16x32 layouts: A[m=lane&15][k=8q+j], B[k=8q+j][n=lane&15],
//   C/D: col=lane&15, row=4q+reg.
// A k-map: q0 j0-3 = xh[src], j4-7 = xh[dst]; q1 j0-7 = attr; q2/q3 zero.
// ===========================================================================
__global__ __launch_bounds__(256) void edge_mlp1(
    const _Float16* __restrict__ xh,      // [N,4] fp16 (L2-resident gathers)
    const char*  __restrict__ rec,        // [E] 24B CSR records
    const float* __restrict__ w1, const float* __restrict__ b1,  // 16x16
    const float* __restrict__ w2, const float* __restrict__ b2,  // 16x16
    _Float16* __restrict__ m2h,           // [E,16] CSR-ordered out (coalesced)
    int E)
{
    __shared__ _Float16 itm[4][8][16][24];
    int tid = threadIdx.x;
    int w = tid >> 6, lane = tid & 63;
    int e16 = lane & 15, q = lane >> 4;
    int ebase = (blockIdx.x * 4 + w) << 7;    // 128 edges per wave
    if (ebase >= E) return;
    int e0 = ebase + lane;
    int e1 = ebase + 64 + lane;

    int s0 = 0, d0 = 0, s1 = 0, d1 = 0;
    if (e0 < E) { int2 p = *(const int2*)(rec + (size_t)e0 * RECB); s0 = p.x; d0 = p.y; }
    if (e1 < E) { int2 p = *(const int2*)(rec + (size_t)e1 * RECB); s1 = p.x; d1 = p.y; }

    half8 B1, B2;
    #pragma unroll
    for (int j = 0; j < 8; ++j) { B1[j] = (_Float16)0.f; B2[j] = (_Float16)0.f; }
    if (q < 2) {
        #pragma unroll
        for (int j = 0; j < 8; ++j) {
            B1[j] = (_Float16)w1[(8 * q + j) * 16 + e16];
            B2[j] = (_Float16)w2[(8 * q + j) * 16 + e16];
        }
    }
    float b1c = b1[e16], b2c = b2[e16];

    half8 A[8];
    #pragma unroll
    for (int t = 0; t < 8; ++t) {
        int tt = t & 3;
        int st = (t < 4) ? __shfl(s0, 16 * tt + e16, 64) : __shfl(s1, 16 * tt + e16, 64);
        int dt = (t < 4) ? __shfl(d0, 16 * tt + e16, 64) : __shfl(d1, 16 * tt + e16, 64);
        half8 a;
        #pragma unroll
        for (int j = 0; j < 8; ++j) a[j] = (_Float16)0.f;
        int et = ebase + 16 * t + e16;
        if (q == 0 && et < E) {
            half4 hs = *(const half4*)(xh + (size_t)st * 4);
            half4 hd = *(const half4*)(xh + (size_t)dt * 4);
            a[0] = hs[0]; a[1] = hs[1]; a[2] = hs[2]; a[3] = hs[3];
            a[4] = hd[0]; a[5] = hd[1]; a[6] = hd[2]; a[7] = hd[3];
        } else if (q == 1 && et < E) {
            a = load_attr(rec, et);
        }
        A[t] = a;
    }

    floatx4 C[8];
    #pragma unroll
    for (int t = 0; t < 8; ++t) {
        floatx4 c = {b1c, b1c, b1c, b1c};
        C[t] = __builtin_amdgcn_mfma_f32_16x16x32_f16(A[t], B1, c, 0, 0, 0);
    }
    #pragma unroll
    for (int t = 0; t < 8; ++t)
        #pragma unroll
        for (int i = 0; i < 4; ++i)
            itm[w][t][4 * q + i][e16] = (_Float16)fmaxf(C[t][i], 0.0f);
    __builtin_amdgcn_wave_barrier();

    half8 A2[8];
    #pragma unroll
    for (int t = 0; t < 8; ++t) {
        half8 a;
        #pragma unroll
        for (int j = 0; j < 8; ++j) a[j] = (_Float16)0.f;
        if (q < 2) a = *(const half8*)&itm[w][t][e16][8 * q];
        A2[t] = a;
    }
    __builtin_amdgcn_wave_barrier();
    floatx4 C2[8];
    #pragma unroll
    for (int t = 0; t < 8; ++t) {
        floatx4 c = {b2c, b2c, b2c, b2c};
        C2[t] = __builtin_amdgcn_mfma_f32_16x16x32_f16(A2[t], B2, c, 0, 0, 0);
    }
    #pragma unroll
    for (int t = 0; t < 8; ++t)
        #pragma unroll
        for (int i = 0; i < 4; ++i)
            itm[w][t][4 * q + i][e16] = (_Float16)C2[t][i];
    __builtin_amdgcn_wave_barrier();

    if (e0 < E) {
        half8 lo = *(const half8*)&itm[w][q][e16][0];
        half8 hi = *(const half8*)&itm[w][q][e16][8];
        *(half8*)(m2h + (size_t)e0 * 16)     = lo;   // coalesced (CSR order)
        *(half8*)(m2h + (size_t)e0 * 16 + 8) = hi;
    }
    if (e1 < E) {
        half8 lo = *(const half8*)&itm[w][q + 4][e16][0];
        half8 hi = *(const half8*)&itm[w][q + 4][e16][8];
        *(half8*)(m2h + (size_t)e1 * 16)     = lo;
        *(half8*)(m2h + (size_t)e1 * 16 + 8) = hi;
    }
}

// ===========================================================================
// conv2 edge-MLP over CSR records: layer-1 C-init via MFMA over gathered h1
// (one 16 B L2 gather per lane per tile); m2h coalesced write.
// A1 k-map (K=32): q0 = h1[src][0:8], q1 = h1[src][8:16],
//                  q2 = h1[dst][0:8], q3 = h1[dst][8:16]
// A2 k-map: q0 = attr (rows 32:40 of W1).
// C = mfma(A1, W1[0:32], mfma(A2, W1[32:40], b1))
// ===========================================================================
__global__ __launch_bounds__(256) void edge_mlp2(
    const _Float16* __restrict__ h1,           // [N,16] fp16
    const char*  __restrict__ rec,
    const float* __restrict__ w1, const float* __restrict__ b1v, // [40,16],[16]
    const float* __restrict__ w2, const float* __restrict__ b2,  // 16x16
    _Float16* __restrict__ m2h, int E)
{
    __shared__ _Float16 itm[4][8][16][24];
    int tid = threadIdx.x;
    int w = tid >> 6, lane = tid & 63;
    int e16 = lane & 15, q = lane >> 4;
    int ebase = (blockIdx.x * 4 + w) << 7;
    if (ebase >= E) return;
    int e0 = ebase + lane;
    int e1 = ebase + 64 + lane;

    int s0 = 0, d0 = 0, s1 = 0, d1 = 0;
    if (e0 < E) { int2 p = *(const int2*)(rec + (size_t)e0 * RECB); s0 = p.x; d0 = p.y; }
    if (e1 < E) { int2 p = *(const int2*)(rec + (size_t)e1 * RECB); s1 = p.x; d1 = p.y; }

    half8 B1, B2e, BL2;
    #pragma unroll
    for (int j = 0; j < 8; ++j) {
        B1[j] = (_Float16)w1[(8 * q + j) * 16 + e16];
        B2e[j] = (_Float16)0.f; BL2[j] = (_Float16)0.f;
    }
    if (q == 0) {
        #pragma unroll
        for (int j = 0; j < 8; ++j)
            B2e[j] = (_Float16)w1[(32 + j) * 16 + e16];
    }
    if (q < 2) {
        #pragma unroll
        for (int j = 0; j < 8; ++j)
            BL2[j] = (_Float16)w2[(8 * q + j) * 16 + e16];
    }
    float b1c = b1v[e16], b2c = b2[e16];

    half8 A1[8];
    #pragma unroll
    for (int t = 0; t < 8; ++t) {
        int tt = t & 3;
        int st = (t < 4) ? __shfl(s0, 16 * tt + e16, 64) : __shfl(s1, 16 * tt + e16, 64);
        int dt = (t < 4) ? __shfl(d0, 16 * tt + e16, 64) : __shfl(d1, 16 * tt + e16, 64);
        int row = (q < 2) ? st : dt;
        A1[t] = *(const half8*)(h1 + (size_t)row * 16 + 8 * (q & 1));
    }

    floatx4 C[8];
    #pragma unroll
    for (int t = 0; t < 8; ++t) {
        half8 a2;
        #pragma unroll
        for (int j = 0; j < 8; ++j) a2[j] = (_Float16)0.f;
        int et = ebase + 16 * t + e16;
        if (q == 0 && et < E)
            a2 = load_attr(rec, et);
        floatx4 c = {b1c, b1c, b1c, b1c};
        c = __builtin_amdgcn_mfma_f32_16x16x32_f16(a2, B2e, c, 0, 0, 0);
        C[t] = __builtin_amdgcn_mfma_f32_16x16x32_f16(A1[t], B1, c, 0, 0, 0);
    }
    #pragma unroll
    for (int t = 0; t < 8; ++t)
        #pragma unroll
        for (int i = 0; i < 4; ++i)
            itm[w][t][4 * q + i][e16] = (_Float16)fmaxf(C[t][i], 0.0f);
    __builtin_amdgcn_wave_barrier();

    half8 A2L[8];
    #pragma unroll
    for (int t = 0; t < 8; ++t) {
        half8 a;
        #pragma unroll
        for (int j = 0; j < 8; ++j) a[j] = (_Float16)0.f;
        if (q < 2) a = *(const half8*)&itm[w][t][e16][8 * q];
        A2L[t] = a;
    }
    __builtin_amdgcn_wave_barrier();
    floatx4 C2[8];
    #pragma unroll
    for (int t = 0; t < 8; ++t) {
        floatx4 c = {b2c, b2c, b2c, b2c};
        C2[t] = __builtin_amdgcn_mfma_f32_16x16x32_f16(A2L[t], BL2, c, 0, 0, 0);
    }
    #pragma unroll
    for (int t = 0; t < 8; ++t)
        #pragma unroll
        for (int i = 0; i < 4; ++i)
            itm[w][t][4 * q + i][e16] = (_Float16)C2[t][i];
    __builtin_amdgcn_wave_barrier();

    if (e0 < E) {
        half8 lo = *(const half8*)&itm[w][q][e16][0];
        half8 hi = *(const half8*)&itm[w][q][e16][8];
        *(half8*)(m2h + (size_t)e0 * 16)     = lo;
        *(half8*)(m2h + (size_t)e0 * 16 + 8) = hi;
    }
    if (e1 < E) {
        half8 lo = *(const half8*)&itm[w][q + 4][e16][0];
        half8 hi = *(const half8*)&itm[w][q + 4][e16][8];
        *(half8*)(m2h + (size_t)e1 * 16)     = lo;
        *(half8*)(m2h + (size_t)e1 * 16 + 8) = hi;
    }
}

// ===========================================================================
// Streaming segment-max (8 lanes/node), packed fp16 max, coalesced m2h.
// Segment n spans pos[n] .. pos[n+1].  acc init 0 == outer ReLU clamp +
// PyG empty fill.
// ===========================================================================
__global__ __launch_bounds__(256) void segmax1_h(
    const _Float16* __restrict__ m2h, const int* __restrict__ pos,
    unsigned int* __restrict__ h1u,     // [N,8] u32 (=16 fp16)
    int N, int E)
{
    int tid = threadIdx.x;
    int n = blockIdx.x * 32 + (tid >> 3);
    if (n >= N) return;
    int g = tid & 7;
    int start = pos[n];
    int end = (n + 1 < N) ? pos[n + 1] : E;

    half8 a0, a1;
    #pragma unroll
    for (int j = 0; j < 8; ++j) { a0[j] = (_Float16)0.f; a1[j] = (_Float16)0.f; }

    for (int k = start + g; k < end; k += 8) {
        half8 v0 = *(const half8*)(m2h + (size_t)k * 16);
        half8 v1 = *(const half8*)(m2h + (size_t)k * 16 + 8);
        a0 = hmax8(a0, v0);
        a1 = hmax8(a1, v1);
    }
    #pragma unroll
    for (int mask = 1; mask < 8; mask <<= 1) {
        H8 x0, x1, y0, y1;
        x0.h = a0; x1.h = a1;
        #pragma unroll
        for (int j = 0; j < 4; ++j) {
            y0.u[j] = __shfl_xor(x0.u[j], mask, 64);
            y1.u[j] = __shfl_xor(x1.u[j], mask, 64);
        }
        a0 = hmax8(a0, y0.h);
        a1 = hmax8(a1, y1.h);
    }
    H8 U0, U1; U0.h = a0; U1.h = a1;
    unsigned int word = (g < 4) ? U0.u[g & 3] : U1.u[g & 3];
    h1u[(size_t)n * 8 + g] = word;
}

__global__ __launch_bounds__(256) void segmax2_head(
    const _Float16* __restrict__ m2h, const int* __restrict__ pos,
    const float* __restrict__ l1w, const float* __restrict__ l1b,
    const float* __restrict__ l2w, const float* __restrict__ l2b,
    float* __restrict__ out, int N, int E)
{
    int tid = threadIdx.x;
    int n = blockIdx.x * 32 + (tid >> 3);
    if (n >= N) return;
    int g = tid & 7;
    int start = pos[n];
    int end = (n + 1 < N) ? pos[n + 1] : E;

    half8 a0, a1;
    #pragma unroll
    for (int j = 0; j < 8; ++j) { a0[j] = (_Float16)0.f; a1[j] = (_Float16)0.f; }

    for (int k = start + g; k < end; k += 8) {
        half8 v0 = *(const half8*)(m2h + (size_t)k * 16);
        half8 v1 = *(const half8*)(m2h + (size_t)k * 16 + 8);
        a0 = hmax8(a0, v0);
        a1 = hmax8(a1, v1);
    }
    #pragma unroll
    for (int mask = 1; mask < 8; mask <<= 1) {
        H8 x0, x1, y0, y1;
        x0.h = a0; x1.h = a1;
        #pragma unroll
        for (int j = 0; j < 4; ++j) {
            y0.u[j] = __shfl_xor(x0.u[j], mask, 64);
            y1.u[j] = __shfl_xor(x1.u[j], mask, 64);
        }
        a0 = hmax8(a0, y0.h);
        a1 = hmax8(a1, y1.h);
    }

    float acc[16];
    #pragma unroll
    for (int j = 0; j < 8; ++j) { acc[j] = (float)a0[j]; acc[8 + j] = (float)a1[j]; }

    float t2[16];
    #pragma unroll
    for (int j = 0; j < 16; ++j) t2[j] = l1b[j];
    #pragma unroll
    for (int kk = 0; kk < 16; ++kk) {
        float ak = acc[kk];
        #pragma unroll
        for (int j = 0; j < 16; ++j) t2[j] = fmaf(ak, l1w[kk * 16 + j], t2[j]);
    }
    float r2 = l2b[0];
    #pragma unroll
    for (int j = 0; j < 16; ++j) r2 = fmaf(fmaxf(t2[j], 0.0f), l2w[j], r2);
    if (g == 0) out[n] = r2;
}

// ===========================================================================
extern "C" void kernel_launch(void* const* d_in, const int* in_sizes, int n_in,
                              void* d_out, int out_size, void* d_ws, size_t ws_size,
                              hipStream_t stream)
{
    const float* x     = (const float*)d_in[0];
    const int*   ei    = (const int*)  d_in[1];
    const float* ea    = (const float*)d_in[2];
    const float* c1_w1 = (const float*)d_in[3];
    const float* c1_b1 = (const float*)d_in[4];
    const float* c1_w2 = (const float*)d_in[5];
    const float* c1_b2 = (const float*)d_in[6];
    const float* c2_w1 = (const float*)d_in[7];
    const float* c2_b1 = (const float*)d_in[8];
    const float* c2_w2 = (const float*)d_in[9];
    const float* c2_b2 = (const float*)d_in[10];
    const float* l1_w  = (const float*)d_in[11];
    const float* l1_b  = (const float*)d_in[12];
    const float* l2_w  = (const float*)d_in[13];
    const float* l2_b  = (const float*)d_in[14];
    float* out = (float*)d_out;

    const int N = in_sizes[0] / 4;   // 100000
    const int E = in_sizes[2] / 8;   // 1600000
    const int nch = (N + CHUNK - 1) / CHUNK;

    const int BLK = 256;
    const int egrid = (E + BLK - 1) / BLK;
    const int ggrid = (N + 31) / 32;
    const int mgrid = (E + 511) / 512;   // 512 edges per block (128/wave)

    size_t szPos = ((size_t)N * 4 + 15) & ~(size_t)15;   // 0.4 MB
    size_t szR   = ((size_t)E * 2 + 15) & ~(size_t)15;   // 3.2 MB
    size_t szXh  = ((size_t)N * 8 + 15) & ~(size_t)15;   // 0.8 MB
    size_t szH1  = ((size_t)N * 32 + 15) & ~(size_t)15;  // 3.2 MB
    size_t szRec = ((size_t)E * RECB + 15) & ~(size_t)15;// 38.4 MB
    size_t szM2h = (size_t)E * 32;                       // 51.2 MB

    size_t pos_off = 0;
    size_t r_off   = pos_off + szPos;
    size_t xh_off  = r_off   + szR;
    size_t h1_off  = xh_off  + szXh;
    size_t rec_off = h1_off  + szH1;
    size_t m2h_off = rec_off + szRec;
    // overlays inside m2h (dead until edge_mlp1 writes it):
    size_t deg_off = m2h_off;
    size_t cs_off  = deg_off + szPos;
    size_t cf_off  = cs_off + 4096;

    int*            pos  = (int*)  ((char*)d_ws + pos_off);
    unsigned short* r    = (unsigned short*)((char*)d_ws + r_off);
    _Float16*       xh   = (_Float16*)((char*)d_ws + xh_off);
    _Float16*       h1   = (_Float16*)((char*)d_ws + h1_off);
    char*           rec  = (char*) ((char*)d_ws + rec_off);
    _Float16*       m2h  = (_Float16*)((char*)d_ws + m2h_off);
    int*            deg  = (int*)  ((char*)d_ws + deg_off);
    int*            csum = (int*)  ((char*)d_ws + cs_off);
    int*            coff = (int*)  ((char*)d_ws + cf_off);

    hipMemsetAsync(deg, 0, (size_t)N * 4, stream);
    rank_cvt<<<egrid, BLK, 0, stream>>>(ei, x, deg, r, xh, E, N);
    scan_chunk_sums<<<nch, BLK, 0, stream>>>(deg, csum, N);
    scan_chunk_off<<<1, 256, 0, stream>>>(csum, coff, nch);
    scan_within_excl<<<nch, BLK, 0, stream>>>(deg, pos, coff, N);
    scatter_rec<<<egrid, BLK, 0, stream>>>(ei, ea, pos, r, rec, E);
    edge_mlp1<<<mgrid, BLK, 0, stream>>>(xh, rec,
                                         c1_w1, c1_b1, c1_w2, c1_b2, m2h, E);
    segmax1_h<<<ggrid, BLK, 0, stream>>>(m2h, pos, (unsigned int*)h1, N, E);
    edge_mlp2<<<mgrid, BLK, 0, stream>>>(h1, rec,
                                         c2_w1, c2_b1, c2_w2, c2_b2, m2h, E);
    segmax2_head<<<ggrid, BLK, 0, stream>>>(m2h, pos, l1_w, l1_b, l2_w, l2_b,
                                            out, N, E);
}